// Round 4
// baseline (184.349 us; speedup 1.0000x reference)
//
#include <hip/hip_runtime.h>
#include <hip/hip_bf16.h>

// ContrastiveLoss: B=4096 rows, D=128 feature dim, C=100 classes.
// loss = -(1/B^2) * sum_c count_c * G_c / (count_c + 1e-12)
//   G_c  = sum_{k: label_k=c} S_k
//   S_k  = sum_j logits[k,j] - B*m_k - B*log(Z_k + 1e-12)
//   logits[k,j] = w_k . a_j,  w_k = (a_k + (a_k @ Cov[l_k]) / (2 T^2)) / T
// 2 dispatches: prep (bf16 conv + W build + control zeroing) and
// main (MFMA flash logits + per-row combine + final loss via tickets).

#define DIM 128
#define TEMP 0.07f
#define PITCH 136  // LDS row pitch in bf16 elems (128 + 8 pad)

typedef __attribute__((ext_vector_type(8))) short short8;
typedef __attribute__((ext_vector_type(4))) float floatx4;

static __device__ __forceinline__ unsigned short f2bf(float f) {
    __hip_bfloat16 h = __float2bfloat16(f);
    union { __hip_bfloat16 h; unsigned short u; } c;
    c.h = h;
    return c.u;
}

// 2 rows per block (256 threads). Writes Abf (bf16 copy of A) and
// Wbf = bf16((a + (a @ Cov[l]) / (2T^2)) / T). Block 0 zeroes G/counts/tickets.
__global__ __launch_bounds__(256) void prep_kernel(
    const float* __restrict__ A, const int* __restrict__ labels,
    const float* __restrict__ Cov, unsigned short* __restrict__ Wbf,
    unsigned short* __restrict__ Abf, double* __restrict__ G,
    int* __restrict__ counts, int* __restrict__ tickets, int C) {
    const float inv2t2 = 1.0f / (2.0f * TEMP * TEMP);
    const float invt = 1.0f / TEMP;
    const int sub = threadIdx.x >> 7;   // which of 2 rows
    const int e = threadIdx.x & 127;
    const int i = blockIdx.x * 2 + sub;
    __shared__ float a[2][DIM];
    float av = A[(size_t)i * DIM + e];
    a[sub][e] = av;
    Abf[(size_t)i * DIM + e] = f2bf(av);
    if (blockIdx.x == 0) {
        int t = threadIdx.x;
        if (t < C) { G[t] = 0.0; counts[t] = 0; }
        if (t >= 128 && t < 128 + 33) tickets[t - 128] = 0;  // 32 mb + 1 global
    }
    __syncthreads();
    int c = labels[i];
    const float* Cp = Cov + (size_t)c * (DIM * DIM) + e;
    float acc = 0.0f;
#pragma unroll 8
    for (int d = 0; d < DIM; ++d) {
        acc = fmaf(a[sub][d], Cp[(size_t)d * DIM], acc);
    }
    Wbf[(size_t)i * DIM + e] = f2bf((av + acc * inv2t2) * invt);
}

// Block = 4 waves (2M x 2N). Block tile: 128 k-rows x 64 j-cols, K=128 unrolled.
// Wave tile: 64x32 via 4(m) x 2(n) mfma_f32_16x16x32_bf16.
// Per-lane online softmax (no cross-lane ops in j-loop); 16-lane merge at end.
// Partials laid out [chunk][row] for coalesced tail reads.
// Tail 1: last of the 16 jsp-blocks per mb merges 128 rows -> per-class G.
// Tail 2: last of all blocks computes the final loss.
__global__ __launch_bounds__(256, 2) void main_kernel(
    const unsigned short* __restrict__ Wbf, const unsigned short* __restrict__ Abf,
    const int* __restrict__ labels,
    float* __restrict__ mP, float* __restrict__ zP, float* __restrict__ sP,
    double* __restrict__ G, int* __restrict__ counts, int* __restrict__ tickets,
    float* __restrict__ out, int B, int Jsplit, int JSWEEP, int nP, int C) {
    __shared__ __align__(16) unsigned short sW[128 * PITCH];
    __shared__ __align__(16) unsigned short sA[64 * PITCH];
    __shared__ int flag;
    __shared__ double sh[256];

    const int mb = blockIdx.x / Jsplit;
    const int jsp = blockIdx.x % Jsplit;
    const int rowBase = mb * 128;
    const int t = threadIdx.x;
    const int wave = t >> 6, lane = t & 63, quad = lane >> 4, l16 = lane & 15;
    const int waveM = wave >> 1, waveN = wave & 1;

    // stage W tile (128 rows x 128 bf16), once
    {
        int row = t >> 1, half = t & 1;
        const unsigned short* src = Wbf + (size_t)(rowBase + row) * DIM + half * 64;
        unsigned short* dst = sW + row * PITCH + half * 64;
#pragma unroll
        for (int i = 0; i < 8; i++)
            *(short8*)(dst + i * 8) = *(const short8*)(src + i * 8);
    }

    float run_m[4][4], run_Z[4][4], run_s[4][4];
#pragma unroll
    for (int a = 0; a < 4; a++)
#pragma unroll
        for (int r = 0; r < 4; r++) {
            run_m[a][r] = -3.4e38f; run_Z[a][r] = 0.f; run_s[a][r] = 0.f;
        }

    const unsigned short* myW = sW + (waveM * 64 + l16) * PITCH;
    const unsigned short* myA = sA + (waveN * 32 + l16) * PITCH;

    for (int js = 0; js < JSWEEP; ++js) {
        __syncthreads();  // protect sA overwrite (and sW on first iter)
        {   // stage A tile (64 rows x 128 bf16)
            int row = t >> 2, q = t & 3;
            int j0 = (jsp * JSWEEP + js) * 64;
            const unsigned short* src = Abf + (size_t)(j0 + row) * DIM + q * 32;
            unsigned short* dst = sA + row * PITCH + q * 32;
#pragma unroll
            for (int i = 0; i < 4; i++)
                *(short8*)(dst + i * 8) = *(const short8*)(src + i * 8);
        }
        __syncthreads();

        floatx4 acc[4][2];
#pragma unroll
        for (int mt = 0; mt < 4; mt++)
#pragma unroll
            for (int nt = 0; nt < 2; nt++) acc[mt][nt] = (floatx4)0.f;

#pragma unroll
        for (int kst = 0; kst < 4; ++kst) {
            const int koff = kst * 32 + quad * 8;
            short8 bfrag[2];
#pragma unroll
            for (int nt = 0; nt < 2; nt++)
                bfrag[nt] = *(const short8*)(myA + nt * 16 * PITCH + koff);
#pragma unroll
            for (int mt = 0; mt < 4; mt++) {
                short8 afrag = *(const short8*)(myW + mt * 16 * PITCH + koff);
#pragma unroll
                for (int nt = 0; nt < 2; nt++)
                    acc[mt][nt] = __builtin_amdgcn_mfma_f32_16x16x32_bf16(
                        afrag, bfrag[nt], acc[mt][nt], 0, 0, 0);
            }
        }

        // per-lane online softmax update (lane's 2 columns only; no shfl)
#pragma unroll
        for (int mt = 0; mt < 4; mt++)
#pragma unroll
            for (int r = 0; r < 4; r++) {
                float v0 = acc[mt][0][r], v1 = acc[mt][1][r];
                float tm = fmaxf(v0, v1);
                float nm = fmaxf(run_m[mt][r], tm);
                run_Z[mt][r] = run_Z[mt][r] * __expf(run_m[mt][r] - nm)
                             + __expf(v0 - nm) + __expf(v1 - nm);
                run_m[mt][r] = nm;
                run_s[mt][r] += v0 + v1;
            }
    }

    // merge across the 16 lanes sharing each row, write partials [chunk][row]
    const int chunk = jsp * 2 + waveN;
#pragma unroll
    for (int mt = 0; mt < 4; mt++)
#pragma unroll
        for (int r = 0; r < 4; r++) {
            float m = run_m[mt][r], Z = run_Z[mt][r], s = run_s[mt][r];
#pragma unroll
            for (int mask = 1; mask < 16; mask <<= 1) {
                float om = __shfl_xor(m, mask);
                float oZ = __shfl_xor(Z, mask);
                float os = __shfl_xor(s, mask);
                float nm = fmaxf(m, om);
                Z = Z * __expf(m - nm) + oZ * __expf(om - nm);
                m = nm;
                s += os;
            }
            if (l16 == r) {
                int row = rowBase + waveM * 64 + mt * 16 + quad * 4 + r;
                size_t idx = (size_t)chunk * B + row;
                mP[idx] = m; zP[idx] = Z; sP[idx] = s;
            }
        }

    // ---- Tail 1: per-mb finisher merges partials for its 128 rows ----
    __threadfence();
    __syncthreads();
    if (t == 0) flag = (atomicAdd(&tickets[mb], 1) == Jsplit - 1);
    __syncthreads();
    if (flag) {
        __threadfence();  // acquire: other blocks' partial stores
        if (t < 128) {
            int k = rowBase + t;
            float m = -3.4e38f, Z = 0.f, s = 0.f;
            for (int p = 0; p < nP; ++p) {
                size_t idx = (size_t)p * B + k;
                float mi = mP[idx];
                float nm = fmaxf(m, mi);
                Z = Z * __expf(m - nm) + zP[idx] * __expf(mi - nm);
                m = nm;
                s += sP[idx];
            }
            double Sk = (double)s - (double)B * (double)m
                        - (double)B * log((double)Z + 1e-12);
            int c = labels[k];
            atomicAdd(&G[c], Sk);
            atomicAdd(&counts[c], 1);
        }
    }

    // ---- Tail 2: global finisher computes the loss ----
    __threadfence();
    __syncthreads();
    if (t == 0) flag = (atomicAdd(&tickets[32], 1) == (int)gridDim.x - 1);
    __syncthreads();
    if (flag) {
        __threadfence();
        double v = 0.0;
        if (t < C) {
            double g = atomicAdd(&G[t], 0.0);       // device-scope coherent read
            double cnt = (double)atomicAdd(&counts[t], 0);
            v = g * (cnt / (cnt + 1e-12));
        }
        sh[t] = v;
        __syncthreads();
        for (int o = 128; o > 0; o >>= 1) {
            if (t < o) sh[t] += sh[t + o];
            __syncthreads();
        }
        if (t == 0)
            out[0] = (float)(-sh[0] / ((double)B * (double)B));
    }
}

extern "C" void kernel_launch(void* const* d_in, const int* in_sizes, int n_in,
                              void* d_out, int out_size, void* d_ws, size_t ws_size,
                              hipStream_t stream) {
    const float* A = (const float*)d_in[0];
    const int* labels = (const int*)d_in[1];
    const float* Cov = (const float*)d_in[2];
    float* out = (float*)d_out;

    int B = in_sizes[0] / DIM;            // 4096
    int C = in_sizes[2] / (DIM * DIM);    // 100
    int Jsplit = 16;
    int JSWEEP = B / (Jsplit * 64);       // 4
    int nP = Jsplit * 2;                  // 32 partials per row

    char* ws = (char*)d_ws;
    unsigned short* Wbf = (unsigned short*)ws;                       // B*128 bf16
    unsigned short* Abf = Wbf + (size_t)B * DIM;                     // B*128 bf16
    float* mP = (float*)(Abf + (size_t)B * DIM);                     // nP*B f32
    float* zP = mP + (size_t)B * nP;
    float* sP = zP + (size_t)B * nP;
    double* G = (double*)(sP + (size_t)B * nP);                      // C doubles
    int* counts = (int*)(G + C);                                     // C ints
    int* tickets = counts + C;                                       // 33 ints

    prep_kernel<<<B / 2, 256, 0, stream>>>(A, labels, Cov, Wbf, Abf,
                                           G, counts, tickets, C);
    main_kernel<<<(B / 128) * Jsplit, 256, 0, stream>>>(
        Wbf, Abf, labels, mP, zP, sP, G, counts, tickets, out,
        B, Jsplit, JSWEEP, nP, C);
}

// Round 5
// 109.438 us; speedup vs baseline: 1.6845x; 1.6845x over previous
//
#include <hip/hip_runtime.h>
#include <hip/hip_bf16.h>

// ContrastiveLoss: B=4096 rows, D=128 feature dim, C=100 classes.
// loss = -(1/B^2) * sum_c count_c * G_c / (count_c + 1e-12)
//   G_c  = sum_{k: label_k=c} S_k
//   S_k  = sum_j logits[k,j] - B*m_k - B*log(Z_k + 1e-12)
//   logits[k,j] = w_k . a_j,  w_k = (a_k + (a_k @ Cov[l_k]) / (2 T^2)) / T
// 4 dispatches: prep (bf16 conv + W build + zero G/counts), main (MFMA flash
// logits, R3-proven), combine (per-row merge -> per-class G), final (loss).
// NOTE: heavy epilogue code must stay OUT of main_kernel — in R4 fusing the
// double-precision tail in dropped VGPR to 68 (spilled MFMA accs, 115us).

#define DIM 128
#define TEMP 0.07f
#define PITCH 136  // LDS row pitch in bf16 elems (128 + 8 pad)

typedef __attribute__((ext_vector_type(8))) short short8;
typedef __attribute__((ext_vector_type(4))) float floatx4;

static __device__ __forceinline__ unsigned short f2bf(float f) {
    __hip_bfloat16 h = __float2bfloat16(f);
    union { __hip_bfloat16 h; unsigned short u; } c;
    c.h = h;
    return c.u;
}

// 2 rows per block (256 threads). Writes Abf (bf16 copy of A) and
// Wbf = bf16((a + (a @ Cov[l]) / (2T^2)) / T). Block 0 zeroes G/counts.
__global__ __launch_bounds__(256) void prep_kernel(
    const float* __restrict__ A, const int* __restrict__ labels,
    const float* __restrict__ Cov, unsigned short* __restrict__ Wbf,
    unsigned short* __restrict__ Abf, double* __restrict__ G,
    int* __restrict__ counts, int C) {
    const float inv2t2 = 1.0f / (2.0f * TEMP * TEMP);
    const float invt = 1.0f / TEMP;
    const int sub = threadIdx.x >> 7;   // which of 2 rows
    const int e = threadIdx.x & 127;
    const int i = blockIdx.x * 2 + sub;
    __shared__ float a[2][DIM];
    float av = A[(size_t)i * DIM + e];
    a[sub][e] = av;
    Abf[(size_t)i * DIM + e] = f2bf(av);
    if (blockIdx.x == 0) {
        int t = threadIdx.x;
        if (t < C) { G[t] = 0.0; counts[t] = 0; }
    }
    __syncthreads();
    int c = labels[i];
    const float* Cp = Cov + (size_t)c * (DIM * DIM) + e;
    float acc = 0.0f;
#pragma unroll 8
    for (int d = 0; d < DIM; ++d) {
        acc = fmaf(a[sub][d], Cp[(size_t)d * DIM], acc);
    }
    Wbf[(size_t)i * DIM + e] = f2bf((av + acc * inv2t2) * invt);
}

// Block = 4 waves (2M x 2N). Block tile: 128 k-rows x 64 j-cols, K=128 unrolled.
// Wave tile: 64x32 via 4(m) x 2(n) mfma_f32_16x16x32_bf16.
// Per-lane online softmax (no cross-lane ops in j-loop); 16-lane merge at end.
// grid = (B/128 m-blocks) * Jsplit; each block sweeps JSWEEP j-tiles of 64.
// (Byte-identical to the R3 version that ran fast.)
__global__ __launch_bounds__(256, 2) void main_kernel(
    const unsigned short* __restrict__ Wbf, const unsigned short* __restrict__ Abf,
    float* __restrict__ mP, float* __restrict__ zP, float* __restrict__ sP,
    int Jsplit, int JSWEEP, int nP) {
    __shared__ __align__(16) unsigned short sW[128 * PITCH];
    __shared__ __align__(16) unsigned short sA[64 * PITCH];

    const int mb = blockIdx.x / Jsplit;
    const int jsp = blockIdx.x % Jsplit;
    const int rowBase = mb * 128;
    const int t = threadIdx.x;
    const int wave = t >> 6, lane = t & 63, quad = lane >> 4, l16 = lane & 15;
    const int waveM = wave >> 1, waveN = wave & 1;

    // stage W tile (128 rows x 128 bf16), once
    {
        int row = t >> 1, half = t & 1;
        const unsigned short* src = Wbf + (size_t)(rowBase + row) * DIM + half * 64;
        unsigned short* dst = sW + row * PITCH + half * 64;
#pragma unroll
        for (int i = 0; i < 8; i++)
            *(short8*)(dst + i * 8) = *(const short8*)(src + i * 8);
    }

    float run_m[4][4], run_Z[4][4], run_s[4][4];
#pragma unroll
    for (int a = 0; a < 4; a++)
#pragma unroll
        for (int r = 0; r < 4; r++) {
            run_m[a][r] = -3.4e38f; run_Z[a][r] = 0.f; run_s[a][r] = 0.f;
        }

    const unsigned short* myW = sW + (waveM * 64 + l16) * PITCH;
    const unsigned short* myA = sA + (waveN * 32 + l16) * PITCH;

    for (int js = 0; js < JSWEEP; ++js) {
        __syncthreads();  // protect sA overwrite (and sW on first iter)
        {   // stage A tile (64 rows x 128 bf16)
            int row = t >> 2, q = t & 3;
            int j0 = (jsp * JSWEEP + js) * 64;
            const unsigned short* src = Abf + (size_t)(j0 + row) * DIM + q * 32;
            unsigned short* dst = sA + row * PITCH + q * 32;
#pragma unroll
            for (int i = 0; i < 4; i++)
                *(short8*)(dst + i * 8) = *(const short8*)(src + i * 8);
        }
        __syncthreads();

        floatx4 acc[4][2];
#pragma unroll
        for (int mt = 0; mt < 4; mt++)
#pragma unroll
            for (int nt = 0; nt < 2; nt++) acc[mt][nt] = (floatx4)0.f;

#pragma unroll
        for (int kst = 0; kst < 4; ++kst) {
            const int koff = kst * 32 + quad * 8;
            short8 bfrag[2];
#pragma unroll
            for (int nt = 0; nt < 2; nt++)
                bfrag[nt] = *(const short8*)(myA + nt * 16 * PITCH + koff);
#pragma unroll
            for (int mt = 0; mt < 4; mt++) {
                short8 afrag = *(const short8*)(myW + mt * 16 * PITCH + koff);
#pragma unroll
                for (int nt = 0; nt < 2; nt++)
                    acc[mt][nt] = __builtin_amdgcn_mfma_f32_16x16x32_bf16(
                        afrag, bfrag[nt], acc[mt][nt], 0, 0, 0);
            }
        }

        // per-lane online softmax update (lane's 2 columns only; no shfl)
#pragma unroll
        for (int mt = 0; mt < 4; mt++)
#pragma unroll
            for (int r = 0; r < 4; r++) {
                float v0 = acc[mt][0][r], v1 = acc[mt][1][r];
                float tm = fmaxf(v0, v1);
                float nm = fmaxf(run_m[mt][r], tm);
                run_Z[mt][r] = run_Z[mt][r] * __expf(run_m[mt][r] - nm)
                             + __expf(v0 - nm) + __expf(v1 - nm);
                run_m[mt][r] = nm;
                run_s[mt][r] += v0 + v1;
            }
    }

    // merge across the 16 lanes sharing each row, then write partials
    const int chunk = jsp * 2 + waveN;
#pragma unroll
    for (int mt = 0; mt < 4; mt++)
#pragma unroll
        for (int r = 0; r < 4; r++) {
            float m = run_m[mt][r], Z = run_Z[mt][r], s = run_s[mt][r];
#pragma unroll
            for (int mask = 1; mask < 16; mask <<= 1) {
                float om = __shfl_xor(m, mask);
                float oZ = __shfl_xor(Z, mask);
                float os = __shfl_xor(s, mask);
                float nm = fmaxf(m, om);
                Z = Z * __expf(m - nm) + oZ * __expf(om - nm);
                m = nm;
                s += os;
            }
            if (l16 == r) {
                int row = rowBase + waveM * 64 + mt * 16 + quad * 4 + r;
                size_t idx = (size_t)row * nP + chunk;
                mP[idx] = m; zP[idx] = Z; sP[idx] = s;
            }
        }
}

// One wave per row k: merge nP partial (m,Z,s) triples, compute S_k,
// accumulate per-class G (double atomics) and class counts.
__global__ __launch_bounds__(64) void combine_kernel(
    const float* __restrict__ mP, const float* __restrict__ zP,
    const float* __restrict__ sP, const int* __restrict__ labels,
    double* __restrict__ G, int* __restrict__ counts, int B, int nP) {
    int k = blockIdx.x;
    int l = threadIdx.x;
    float m = -3.4e38f, Z = 0.0f, s = 0.0f;
    if (l < nP) {
        size_t idx = (size_t)k * nP + l;
        m = mP[idx]; Z = zP[idx]; s = sP[idx];
    }
    float M = m;
#pragma unroll
    for (int o = 32; o > 0; o >>= 1) M = fmaxf(M, __shfl_xor(M, o));
    float zt = Z * __expf(m - M);
    float st = s;
#pragma unroll
    for (int o = 32; o > 0; o >>= 1) {
        zt += __shfl_xor(zt, o);
        st += __shfl_xor(st, o);
    }
    if (l == 0) {
        double Sk = (double)st - (double)B * (double)M
                    - (double)B * log((double)zt + 1e-12);
        int c = labels[k];
        atomicAdd(&G[c], Sk);
        atomicAdd(&counts[c], 1);
    }
}

__global__ __launch_bounds__(128) void final_kernel(
    const double* __restrict__ G, const int* __restrict__ counts,
    float* __restrict__ out, int C, double invB2) {
    __shared__ double sh[128];
    int t = threadIdx.x;
    double v = 0.0;
    if (t < C) {
        double cnt = (double)counts[t];
        v = G[t] * (cnt / (cnt + 1e-12));
    }
    sh[t] = v;
    __syncthreads();
    for (int o = 64; o > 0; o >>= 1) {
        if (t < o) sh[t] += sh[t + o];
        __syncthreads();
    }
    if (t == 0) out[0] = (float)(-sh[0] * invB2);
}

extern "C" void kernel_launch(void* const* d_in, const int* in_sizes, int n_in,
                              void* d_out, int out_size, void* d_ws, size_t ws_size,
                              hipStream_t stream) {
    const float* A = (const float*)d_in[0];
    const int* labels = (const int*)d_in[1];
    const float* Cov = (const float*)d_in[2];
    float* out = (float*)d_out;

    int B = in_sizes[0] / DIM;            // 4096
    int C = in_sizes[2] / (DIM * DIM);    // 100
    int Jsplit = 16;
    int JSWEEP = B / (Jsplit * 64);       // 4
    int nP = Jsplit * 2;                  // 32 partials per row

    char* ws = (char*)d_ws;
    unsigned short* Wbf = (unsigned short*)ws;                       // B*128 bf16
    unsigned short* Abf = Wbf + (size_t)B * DIM;                     // B*128 bf16
    float* mP = (float*)(Abf + (size_t)B * DIM);                     // B*nP f32
    float* zP = mP + (size_t)B * nP;
    float* sP = zP + (size_t)B * nP;
    double* G = (double*)(sP + (size_t)B * nP);                      // C doubles
    int* counts = (int*)(G + C);                                     // C ints

    prep_kernel<<<B / 2, 256, 0, stream>>>(A, labels, Cov, Wbf, Abf,
                                           G, counts, C);
    main_kernel<<<(B / 128) * Jsplit, 256, 0, stream>>>(Wbf, Abf, mP, zP, sP,
                                                        Jsplit, JSWEEP, nP);
    combine_kernel<<<B, 64, 0, stream>>>(mP, zP, sP, labels, G, counts, B, nP);
    final_kernel<<<1, 128, 0, stream>>>(G, counts, out, C,
                                        1.0 / ((double)B * (double)B));
}